// Round 6
// baseline (220.324 us; speedup 1.0000x reference)
//
#include <hip/hip_runtime.h>

typedef unsigned int u32;
typedef float v2f __attribute__((ext_vector_type(2)));

#define DIM 16384
#define NT  512

// Swizzle v3 (HW-validated R4): s1=y1^y4, s2=y2^y7, s3=y3^y6^y8. Conflict-free
// under the 8-lane(b128)/16-lane(b64) phase model for all pass patterns.
__host__ __device__ constexpr u32 swz0(u32 d) {
    u32 b1 = (d >> 4) & 1u;
    u32 b2 = (d >> 7) & 1u;
    u32 b3 = ((d >> 6) ^ (d >> 8)) & 1u;
    return d ^ (b1 << 1) ^ (b2 << 2) ^ (b3 << 3);
}

// CNOT-ring basis map (HW-validated R2/R3): M(y)_b = XOR_{p>=b} y_p (b<=12),
// M(y)_13 = XOR_{p<=12} y_p. GF(2)-linear.
__host__ __device__ constexpr u32 mmap(u32 y) {
    u32 s = y;
    s ^= s >> 1; s ^= s >> 2; s ^= s >> 4; s ^= s >> 8;
    return (s & 0x1FFFu) | (((s ^ (y >> 13)) & 1u) << 13);
}

// Packed rotation: 2 v_pk_mul_f32 + 2 v_pk_fma_f32 (re,im in one v2f).
// ns = -s hoisted per gate. Bit-identical rounding to scalar fma.
__device__ __forceinline__ void rot2(v2f& a0, v2f& a1, v2f cv, v2f sv, v2f nsv) {
    v2f t0 = cv * a0;
    v2f t1 = cv * a1;
    v2f n0 = __builtin_elementwise_fma(nsv, a1, t0);
    v2f n1 = __builtin_elementwise_fma(sv,  a0, t1);
    a0 = n0; a1 = n1;
}

// RY on register-space bit D across all 32 register amps.
template<int D>
__device__ __forceinline__ void gate32(v2f (&am)[32], float c, float s) {
    v2f cv = {c, c}, sv = {s, s}, nsv = {-s, -s};
    #pragma unroll
    for (int r = 0; r < 32; ++r) if (!(r & D)) rot2(am[r], am[r | D], cv, sv, nsv);
}

// Pass A: varying {0,1,11,12,13}; gates ascending D=1,2,4,8,16 (y0,y1,y11,y12,y13).
template<int L>
__device__ __forceinline__ void passA(int tid, float* smem, v2f (&am)[32]) {
    float4* stv = (float4*)smem;
    const float* angC = smem + 32768;
    const float* angS = smem + 32768 + 48;
    u32 sbase = swz0((u32)tid << 2);
    if (L > 0) {
        #pragma unroll
        for (int h = 0; h < 8; ++h) {
            #pragma unroll
            for (int m = 0; m < 2; ++m) {
                u32 idx = (sbase ^ swz0(((u32)h << 11) | ((u32)m << 1))) >> 1;
                float4 v = stv[idx];
                int r = h * 4 + m * 2;
                am[r].x     = v.x; am[r].y     = v.y;
                am[r + 1].x = v.z; am[r + 1].y = v.w;
            }
        }
    }
    gate32< 1>(am, angC[L * 16 +  0], angS[L * 16 +  0]);  // y0
    gate32< 2>(am, angC[L * 16 +  1], angS[L * 16 +  1]);  // y1
    gate32< 4>(am, angC[L * 16 + 11], angS[L * 16 + 11]);  // y11
    gate32< 8>(am, angC[L * 16 + 12], angS[L * 16 + 12]);  // y12
    gate32<16>(am, angC[L * 16 + 13], angS[L * 16 + 13]);  // y13
    #pragma unroll
    for (int h = 0; h < 8; ++h) {
        #pragma unroll
        for (int m = 0; m < 2; ++m) {
            u32 idx = (sbase ^ swz0(((u32)h << 11) | ((u32)m << 1))) >> 1;
            int r = h * 4 + m * 2;
            stv[idx] = make_float4(am[r].x, am[r].y, am[r + 1].x, am[r + 1].y);
        }
    }
    __syncthreads();
}

// Pass B: varying {6..10}; gates ascending (y6..y10). b64 accesses.
template<int L>
__device__ __forceinline__ void passB(int tid, float* smem, v2f (&am)[32]) {
    float2* st2 = (float2*)smem;
    const float* angC = smem + 32768;
    const float* angS = smem + 32768 + 48;
    u32 ybase = ((u32)tid & 63u) | (((u32)tid >> 6) << 11);
    u32 sbase = swz0(ybase);
    #pragma unroll
    for (int j = 0; j < 32; ++j) {
        float2 v = st2[sbase ^ swz0((u32)j << 6)];
        am[j].x = v.x; am[j].y = v.y;
    }
    gate32< 1>(am, angC[L * 16 +  6], angS[L * 16 +  6]);
    gate32< 2>(am, angC[L * 16 +  7], angS[L * 16 +  7]);
    gate32< 4>(am, angC[L * 16 +  8], angS[L * 16 +  8]);
    gate32< 8>(am, angC[L * 16 +  9], angS[L * 16 +  9]);
    gate32<16>(am, angC[L * 16 + 10], angS[L * 16 + 10]);
    #pragma unroll
    for (int j = 0; j < 32; ++j) {
        st2[sbase ^ swz0((u32)j << 6)] = make_float2(am[j].x, am[j].y);
    }
    __syncthreads();
}

// Pass C: varying {0,2,3,4,5}; gates y2..y5; then M-scatter (L<2) or fused
// measurement (L==2).
template<int L>
__device__ __forceinline__ void passC(int tid, float* smem, v2f (&am)[32],
                                      float& acc, float W0) {
    float2* st2 = (float2*)smem;
    float4* stv = (float4*)smem;
    const float* angC  = smem + 32768;
    const float* angS  = smem + 32768 + 48;
    const float* lutLo = smem + 32768 + 96;
    const float* lutHi = smem + 32768 + 96 + 128;
    u32 ybase = (((u32)tid & 1u) << 1) | (((u32)tid >> 1) << 6);
    u32 sbase = swz0(ybase);
    #pragma unroll
    for (int h = 0; h < 16; ++h) {
        u32 idx = (sbase ^ swz0((u32)h << 2)) >> 1;
        float4 v = stv[idx];
        int r = h * 2;
        am[r].x     = v.x; am[r].y     = v.y;
        am[r + 1].x = v.z; am[r + 1].y = v.w;
    }
    gate32< 2>(am, angC[L * 16 + 2], angS[L * 16 + 2]);  // y2
    gate32< 4>(am, angC[L * 16 + 3], angS[L * 16 + 3]);
    gate32< 8>(am, angC[L * 16 + 4], angS[L * 16 + 4]);
    gate32<16>(am, angC[L * 16 + 5], angS[L * 16 + 5]);
    if (L < 2) {
        // scatter targets other threads' read slots: drain reads block-wide first
        __syncthreads();
        u32 pbase = swz0(mmap(ybase));
        #pragma unroll
        for (int h = 0; h < 16; ++h) {
            #pragma unroll
            for (int q = 0; q < 2; ++q) {
                u32 slot = pbase ^ swz0(mmap(((u32)h << 2) | (u32)q));
                int r = h * 2 + q;
                st2[slot] = make_float2(am[r].x, am[r].y);
            }
        }
        __syncthreads();
    } else {
        u32 myb = mmap(ybase);
        #pragma unroll
        for (int h = 0; h < 16; ++h) {
            #pragma unroll
            for (int q = 0; q < 2; ++q) {
                u32 yp = myb ^ mmap(((u32)h << 2) | (u32)q);
                int r = h * 2 + q;
                float p  = fmaf(am[r].x, am[r].x, am[r].y * am[r].y);
                float wv = W0 - 2.0f * (lutLo[yp & 127u] + lutHi[yp >> 7]);
                acc = fmaf(wv, p, acc);
            }
        }
    }
}

__global__ __launch_bounds__(NT, 2) void qsim_kernel(
    const float* __restrict__ sreal, const float* __restrict__ simag,
    const float* __restrict__ wts,   const float* __restrict__ hw,
    const float* __restrict__ hb,    float* __restrict__ out)
{
    extern __shared__ float smem[];
    float* angC   = smem + 32768;
    float* angS   = angC + 48;
    float* lutLo  = angS + 48;
    float* lutHi  = lutLo + 128;
    float* redbuf = lutHi + 128;

    int tid = threadIdx.x;
    int b   = blockIdx.x;

    // global load, pass-A register layout: float4 (h<<9)|tid covers y = (h<<11)|(tid<<2)|{0..3}
    const float4* pr = (const float4*)(sreal + (size_t)b * DIM);
    const float4* pi = (const float4*)(simag + (size_t)b * DIM);
    float4 vr[8], vi[8];
    #pragma unroll
    for (int h = 0; h < 8; ++h) {
        vr[h] = pr[(h << 9) | tid];
        vi[h] = pi[(h << 9) | tid];
    }

    // block-uniform setup: summed half-angles (3 RYs/wire/layer compose) + head LUTs
    if (tid < 42) {
        int l = tid / 14, bb = tid % 14, q = 13 - bb;   // bit bb <-> wire 13-bb
        float a = 0.5f * (wts[l * 42 + q] + wts[l * 42 + 14 + q] + wts[l * 42 + 28 + q]);
        angC[l * 16 + bb] = cosf(a);
        angS[l * 16 + bb] = sinf(a);
    } else if (tid >= 64 && tid < 192) {
        int i = tid - 64;           // low 7 index bits -> wires 13..7
        float ssum = 0.f;
        for (int bb = 0; bb < 7; ++bb) if ((i >> bb) & 1) ssum += hw[13 - bb];
        lutLo[i] = ssum;
    } else if (tid >= 192 && tid < 320) {
        int i = tid - 192;          // high 7 index bits -> wires 6..0
        float ssum = 0.f;
        for (int bb = 0; bb < 7; ++bb) if ((i >> bb) & 1) ssum += hw[6 - bb];
        lutHi[i] = ssum;
    }

    v2f am[32];
    #pragma unroll
    for (int h = 0; h < 8; ++h) {
        am[h * 4 + 0].x = vr[h].x; am[h * 4 + 0].y = vi[h].x;
        am[h * 4 + 1].x = vr[h].y; am[h * 4 + 1].y = vi[h].y;
        am[h * 4 + 2].x = vr[h].z; am[h * 4 + 2].y = vi[h].z;
        am[h * 4 + 3].x = vr[h].w; am[h * 4 + 3].y = vi[h].w;
    }

    __syncthreads();
    float W0  = lutLo[127] + lutHi[127];   // sum of all head weights
    float acc = 0.f;

    passA<0>(tid, smem, am);
    passB<0>(tid, smem, am);
    passC<0>(tid, smem, am, acc, W0);
    passA<1>(tid, smem, am);
    passB<1>(tid, smem, am);
    passC<1>(tid, smem, am, acc, W0);
    passA<2>(tid, smem, am);
    passB<2>(tid, smem, am);
    passC<2>(tid, smem, am, acc, W0);

    // block reduction
    #pragma unroll
    for (int off = 32; off > 0; off >>= 1) acc += __shfl_xor(acc, off, 64);
    if ((tid & 63) == 0) redbuf[tid >> 6] = acc;
    __syncthreads();
    if (tid == 0) {
        float tot = hb[0];
        #pragma unroll
        for (int i = 0; i < 8; ++i) tot += redbuf[i];
        out[b] = tot;
    }
}

extern "C" void kernel_launch(void* const* d_in, const int* in_sizes, int n_in,
                              void* d_out, int out_size, void* d_ws, size_t ws_size,
                              hipStream_t stream)
{
    const float* sreal = (const float*)d_in[0];
    const float* simag = (const float*)d_in[1];
    const float* wts   = (const float*)d_in[2];
    const float* hw    = (const float*)d_in[3];
    const float* hb    = (const float*)d_in[4];
    float* out = (float*)d_out;

    int batch = in_sizes[0] / DIM;
    size_t smem_bytes = (32768 + 48 + 48 + 128 + 128 + 16) * sizeof(float);  // 132.5 KB < 160 KB

    (void)hipFuncSetAttribute((const void*)qsim_kernel,
                              hipFuncAttributeMaxDynamicSharedMemorySize, (int)smem_bytes);
    qsim_kernel<<<dim3(batch), dim3(NT), smem_bytes, stream>>>(sreal, simag, wts, hw, hb, out);
}